// Round 3
// baseline (417.138 us; speedup 1.0000x reference)
//
#include <hip/hip_runtime.h>

#define NPIX   768
#define PP     256
#define NTERMS 128
#define EPSF   1e-15f
#define PLANEF (NPIX * NPIX)     // floats per plane
#define ROWF   (3 * NPIX)        // floats per 3-row chunk = 2304 (9216 B)

typedef float f32x4 __attribute__((ext_vector_type(4)));
typedef __attribute__((address_space(1))) const void* gas_p;   // global
typedef __attribute__((address_space(3))) void*       las_p;   // LDS

// ---------------------------------------------------------------------------
// Closed-form CLIMB area for one 3x3 patch (identical to the passing version).
// ---------------------------------------------------------------------------
__device__ __forceinline__ float climb_area(const float f[9])
{
    float sum = 0.f;
    #pragma unroll
    for (int m = 0; m < 9; ++m) sum += f[m];
    float mean = sum * (1.f / 9.f);

    float a = (f[2] + f[5] + f[8] - f[0] - f[3] - f[6]) * (1.f / 3.f);
    float b = (f[6] + f[7] + f[8] - f[0] - f[1] - f[2]) * (1.f / 3.f);
    float c = mean - 0.5f * (a + b);

    if (a == 0.f) a = EPSF;
    if (b == 0.f) b = EPSF;
    if (c == 0.f) c = EPSF;

    float x1 = (-b - c) / a;
    float x2 = -c / a;
    float lo = fminf(x1, x2);
    float hi = fmaxf(x1, x2);
    x1 = fmaxf(lo, 0.f);
    x2 = fminf(hi, 1.f);

    float cb = -c / b;
    float ab = 0.5f * (a / b);
    float d = x1 + cb * x2 - ab * x2 * x2 - cb * x1 + ab * x1 * x1;

    d = (d >= 0.5f) ? d : 1.f - d;
    d = (mean >= 0.f) ? d : 1.f - d;

    bool allpos = true, allnp = true, anyz = false;
    #pragma unroll
    for (int m = 0; m < 9; ++m) {
        allpos = allpos && (f[m] > 0.f);
        allnp  = allnp  && (f[m] <= 0.f);
        anyz   = anyz   || (f[m] == 0.f);
    }
    if (allpos) d = 1.f;
    if (allnp)  d = 0.f;
    if (anyz)   d = (d > 0.f) ? 1.f : 0.f;

    return fminf(fmaxf(d, 0.f), 1.f);
}

// ---------------------------------------------------------------------------
// Fully fused kernel: one block per output row r (grid = 256, block = 256).
//
// Block r needs basis rows 3r..3r+2 of every plane: ONE contiguous 9216 B
// chunk per plane. Chunks are staged directly into LDS with
// global_load_lds, TRIPLE-buffered, counted vmcnt + raw s_barrier (never
// __syncthreads in the loop — it would emit vmcnt(0) and drain the
// prefetch pipeline). 18 KB/CU in flight = 2x the BW*latency product
// (6.3 TB/s * 375 ns / 256 CU = 9.2 KB).
//
// Per-wave staging is UNIFORM (3 GLL ops/wave/plane):
//   GLL16 #1: floats [wv*256        , +256)   (64 lanes x 16 B = 1 KB)
//   GLL16 #2: floats [1024 + wv*256 , +256)
//   GLL4  #3: floats [2048 + wv*64  , +64)    (64 lanes x 4 B = 256 B)
// -> every wave has exactly 3 outstanding loads per staged plane, so the
// counted waits are the same immediates for all waves: vmcnt(6)/(3)/(0).
//
// Compute per plane: 9 LDS scalar reads (word stride 3, coprime with 32
// banks -> 2-way aliasing = free) + 9 FMAs into f[9]. Epilogue: climb.
// W never materializes; d_ws unused; one launch total.
// ---------------------------------------------------------------------------
__global__ __launch_bounds__(256) void fused_kernel(
    const float* __restrict__ basis,
    const float* __restrict__ coeffs,
    const float* __restrict__ wavel,
    float* __restrict__ out)
{
    __shared__ float sc[NTERMS];
    __shared__ float lds[3][ROWF];           // 3 x 9216 B = 27.6 KB

    const int tid  = threadIdx.x;
    const int lane = tid & 63;
    const int wv   = tid >> 6;               // 0..3
    const int r    = blockIdx.x;             // output row

    if (tid < NTERMS) sc[tid] = coeffs[tid];
    __syncthreads();                          // drains the coeffs load too

    const float* __restrict__ gbase = basis + (size_t)r * ROWF;

    // Stage plane (pl) into LDS slot (sl): 3 GLL ops per wave, uniform.
    #define STAGE(sl, pl) do {                                                  \
        const float* gs_ = gbase + (size_t)(pl) * PLANEF;                       \
        __builtin_amdgcn_global_load_lds(                                       \
            (gas_p)(gs_ + (wv << 8) + (lane << 2)),                             \
            (las_p)(&lds[(sl)][(wv) << 8]), 16, 0, 0);                          \
        __builtin_amdgcn_global_load_lds(                                       \
            (gas_p)(gs_ + 1024 + (wv << 8) + (lane << 2)),                      \
            (las_p)(&lds[(sl)][1024 + ((wv) << 8)]), 16, 0, 0);                 \
        __builtin_amdgcn_global_load_lds(                                       \
            (gas_p)(gs_ + 2048 + (wv << 6) + lane),                             \
            (las_p)(&lds[(sl)][2048 + ((wv) << 6)]), 4, 0, 0);                  \
    } while (0)

    #define COMPUTE(n_, sl_) do {                                               \
        const float cn_ = sc[(n_)];                                             \
        const float* __restrict__ L_ = lds[(sl_)];                              \
        _Pragma("unroll")                                                       \
        for (int s_ = 0; s_ < 3; ++s_)                                          \
            _Pragma("unroll")                                                   \
            for (int q_ = 0; q_ < 3; ++q_)                                      \
                f[q_ * 3 + s_] = fmaf(L_[s_ * NPIX + x0 + q_], cn_,             \
                                      f[q_ * 3 + s_]);                          \
    } while (0)

    float f[9];
    #pragma unroll
    for (int m = 0; m < 9; ++m) f[m] = 0.f;
    const int x0 = 3 * tid;

    // Prologue: 2 planes in flight.
    STAGE(0, 0);
    STAGE(1, 1);

    int cur = 0, nxt = 2;
    #pragma unroll 1
    for (int n = 0; n < NTERMS - 2; ++n) {
        STAGE(nxt, n + 2);
        // 9 loads outstanding (planes n, n+1, n+2); wait for plane n's 3.
        asm volatile("s_waitcnt vmcnt(6)" ::: "memory");
        __builtin_amdgcn_s_barrier();
        COMPUTE(n, cur);
        asm volatile("" ::: "memory");        // pin LDS reads before barrier
        __builtin_amdgcn_s_barrier();          // slot cur is now reusable
        cur = (cur == 2) ? 0 : cur + 1;
        nxt = (nxt == 2) ? 0 : nxt + 1;
    }

    // n = 126: planes 126,127 outstanding -> wait for 126's 3 loads.
    asm volatile("s_waitcnt vmcnt(3)" ::: "memory");
    __builtin_amdgcn_s_barrier();
    COMPUTE(NTERMS - 2, cur);
    asm volatile("" ::: "memory");
    __builtin_amdgcn_s_barrier();
    cur = (cur == 2) ? 0 : cur + 1;

    // n = 127: drain everything.
    asm volatile("s_waitcnt vmcnt(0)" ::: "memory");
    __builtin_amdgcn_s_barrier();
    COMPUTE(NTERMS - 1, cur);

    out[r * PP + tid] = climb_area(f) * 0.5f * wavel[0];

    #undef STAGE
    #undef COMPUTE
}

extern "C" void kernel_launch(void* const* d_in, const int* in_sizes, int n_in,
                              void* d_out, int out_size, void* d_ws, size_t ws_size,
                              hipStream_t stream)
{
    const float* basis  = (const float*)d_in[0];  // 128*768*768 f32
    const float* coeffs = (const float*)d_in[1];  // 128 f32
    const float* wavel  = (const float*)d_in[2];  // 1 f32
    float* out = (float*)d_out;                   // 256*256 f32
    (void)d_ws; (void)ws_size;

    fused_kernel<<<PP, 256, 0, stream>>>(basis, coeffs, wavel, out);
}

// Round 4
// 371.663 us; speedup vs baseline: 1.1224x; 1.1224x over previous
//
#include <hip/hip_runtime.h>

#define NPIX   768
#define PP     256
#define NTERMS 128
#define EPSF   1e-15f

// Native Clang vector type: __builtin_nontemporal_load requires a true
// vector type (HIP's float4 is a class and is rejected).
typedef float f32x4 __attribute__((ext_vector_type(4)));

#define NV4   (NPIX * NPIX / 4)   // 147456 f32x4 per 768x768 plane

// ---------------------------------------------------------------------------
// Kernel 1: W[t] = sum_n basis[n][t] * coeffs[n]
//
// BEST MEASURED SHAPE (372.35 us total, round 1; prior session 371.9):
// 768 block-positions, each owning the same 192 consecutive f32x4 (3 KB) of
// every plane; per plane a wave reads its 3 KB contiguously (3 loads/lane at
// +0/+1KB/+2KB immediate offsets), planes in PAIRS (2 concurrent 3 KB
// streams per wave). 256 threads/block: the 128 planes are split across the
// 4 waves (wave w accumulates planes 32w..32w+31) + 12 KB LDS cross-wave
// reduction.
//
// Evidence from this session (rounds 0-3): dur_us is dominated by ~366 us of
// harness poison-fill traffic (2 x 1.2 GB at ~6.6 TB/s) that BW-shares the
// timed window with our kernels; this shape achieves 7.3 TB/s COMBINED
// (above the fill-only rate). Both redesigns — contiguous 8-plane sweep
// (r2, +28 us) and 9KB GLL triple-buffer fused (r3, +45 us) — regressed by
// interleaving worse with the fill stream. Do not change the DRAM pattern.
// ---------------------------------------------------------------------------
__global__ __launch_bounds__(256) void latent_kernel(
    const float* __restrict__ basis,
    const float* __restrict__ coeffs,
    float* __restrict__ W)
{
    __shared__ float sc[NTERMS];
    __shared__ f32x4 red[4][192];          // per-wave partials, 12 KB

    if (threadIdx.x < NTERMS) sc[threadIdx.x] = coeffs[threadIdx.x];
    __syncthreads();

    const int lane = threadIdx.x & 63;
    const int wv   = threadIdx.x >> 6;     // 0..3
    const int t0   = blockIdx.x * 192 + lane;   // first of 3 f32x4 (shared by all waves)
    const f32x4* __restrict__ b4 = (const f32x4*)basis;

    f32x4 a0 = {0.f, 0.f, 0.f, 0.f};
    f32x4 a1 = {0.f, 0.f, 0.f, 0.f};
    f32x4 a2 = {0.f, 0.f, 0.f, 0.f};

    const int n0 = wv * (NTERMS / 4);      // this wave's 32 planes

    #pragma unroll 1
    for (int n = n0; n < n0 + NTERMS / 4; n += 2) {
        const f32x4* __restrict__ pa = b4 + (long)n * NV4 + t0;
        const f32x4* __restrict__ pb = pa + NV4;
        // plane n: one 3 KB contiguous chunk (offsets are immediates)
        f32x4 v0 = __builtin_nontemporal_load(pa);
        f32x4 v1 = __builtin_nontemporal_load(pa + 64);
        f32x4 v2 = __builtin_nontemporal_load(pa + 128);
        // plane n+1: second stream
        f32x4 v3 = __builtin_nontemporal_load(pb);
        f32x4 v4 = __builtin_nontemporal_load(pb + 64);
        f32x4 v5 = __builtin_nontemporal_load(pb + 128);

        const float ca = sc[n];
        const float cb = sc[n + 1];
        a0.x = fmaf(v0.x, ca, a0.x); a0.y = fmaf(v0.y, ca, a0.y);
        a0.z = fmaf(v0.z, ca, a0.z); a0.w = fmaf(v0.w, ca, a0.w);
        a1.x = fmaf(v1.x, ca, a1.x); a1.y = fmaf(v1.y, ca, a1.y);
        a1.z = fmaf(v1.z, ca, a1.z); a1.w = fmaf(v1.w, ca, a1.w);
        a2.x = fmaf(v2.x, ca, a2.x); a2.y = fmaf(v2.y, ca, a2.y);
        a2.z = fmaf(v2.z, ca, a2.z); a2.w = fmaf(v2.w, ca, a2.w);
        a0.x = fmaf(v3.x, cb, a0.x); a0.y = fmaf(v3.y, cb, a0.y);
        a0.z = fmaf(v3.z, cb, a0.z); a0.w = fmaf(v3.w, cb, a0.w);
        a1.x = fmaf(v4.x, cb, a1.x); a1.y = fmaf(v4.y, cb, a1.y);
        a1.z = fmaf(v4.z, cb, a1.z); a1.w = fmaf(v4.w, cb, a1.w);
        a2.x = fmaf(v5.x, cb, a2.x); a2.y = fmaf(v5.y, cb, a2.y);
        a2.z = fmaf(v5.z, cb, a2.z); a2.w = fmaf(v5.w, cb, a2.w);
    }

    // cross-wave reduction: all 4 waves cover the SAME 192 f32x4 positions.
    red[wv][lane]       = a0;
    red[wv][lane + 64]  = a1;
    red[wv][lane + 128] = a2;
    __syncthreads();

    if (threadIdx.x < 192) {
        f32x4 s = red[0][threadIdx.x];
        s += red[1][threadIdx.x];
        s += red[2][threadIdx.x];
        s += red[3][threadIdx.x];
        f32x4* __restrict__ W4 = (f32x4*)W;
        W4[blockIdx.x * 192 + threadIdx.x] = s;
    }
}

// ---------------------------------------------------------------------------
// Closed-form CLIMB area for one 3x3 patch.
// f[m], m = q*3+s  corresponds to sample at x = s/2, y = q/2.
// Least-squares plane fit (regressors orthogonal after centering):
//   a = (sum_{s=2} - sum_{s=0}) / 3
//   b = (sum_{q=2} - sum_{q=0}) / 3
//   c = mean - 0.5*(a+b)
// ---------------------------------------------------------------------------
__device__ __forceinline__ float climb_area(const float f[9])
{
    float sum = 0.f;
    #pragma unroll
    for (int m = 0; m < 9; ++m) sum += f[m];
    float mean = sum * (1.f / 9.f);

    float a = (f[2] + f[5] + f[8] - f[0] - f[3] - f[6]) * (1.f / 3.f);
    float b = (f[6] + f[7] + f[8] - f[0] - f[1] - f[2]) * (1.f / 3.f);
    float c = mean - 0.5f * (a + b);

    if (a == 0.f) a = EPSF;
    if (b == 0.f) b = EPSF;
    if (c == 0.f) c = EPSF;

    float x1 = (-b - c) / a;
    float x2 = -c / a;
    float lo = fminf(x1, x2);
    float hi = fmaxf(x1, x2);
    x1 = fmaxf(lo, 0.f);
    x2 = fminf(hi, 1.f);

    float cb = -c / b;
    float ab = 0.5f * (a / b);
    float d = x1 + cb * x2 - ab * x2 * x2 - cb * x1 + ab * x1 * x1;

    d = (d >= 0.5f) ? d : 1.f - d;
    d = (mean >= 0.f) ? d : 1.f - d;

    bool allpos = true, allnp = true, anyz = false;
    #pragma unroll
    for (int m = 0; m < 9; ++m) {
        allpos = allpos && (f[m] > 0.f);
        allnp  = allnp  && (f[m] <= 0.f);
        anyz   = anyz   || (f[m] == 0.f);
    }
    if (allpos) d = 1.f;
    if (allnp)  d = 0.f;
    if (anyz)   d = (d > 0.f) ? 1.f : 0.f;

    return fminf(fmaxf(d, 0.f), 1.f);
}

// ---------------------------------------------------------------------------
// Kernel 2: one thread per output pixel (r,p), t = r*256 + p.
//   f[q*3+s] = W[3r+s][3p+q]
//   out = area * ideal_wavel / 2     (pi cancels)
// W is 2.36 MB, L2-resident right after kernel 1.
// ---------------------------------------------------------------------------
__global__ __launch_bounds__(256) void climb_kernel(
    const float* __restrict__ W,
    const float* __restrict__ wavel,
    float* __restrict__ out)
{
    const int t = blockIdx.x * 256 + threadIdx.x;   // 0 .. 65535
    const int r = t >> 8;
    const int p = t & 255;

    const float* __restrict__ base = W + (3 * r) * NPIX + 3 * p;
    float f[9];
    #pragma unroll
    for (int s = 0; s < 3; ++s)
        #pragma unroll
        for (int q = 0; q < 3; ++q)
            f[q * 3 + s] = base[s * NPIX + q];

    out[t] = climb_area(f) * 0.5f * wavel[0];
}

// ---------------------------------------------------------------------------
// Fallback: fully fused (used only if d_ws can't hold W). Same math,
// basis read directly with 9 scalar loads per term (aggregate-coalesced).
// ---------------------------------------------------------------------------
__global__ __launch_bounds__(256) void fused_kernel(
    const float* __restrict__ basis,
    const float* __restrict__ coeffs,
    const float* __restrict__ wavel,
    float* __restrict__ out)
{
    __shared__ float sc[NTERMS];
    if (threadIdx.x < NTERMS) sc[threadIdx.x] = coeffs[threadIdx.x];
    __syncthreads();

    const int t = blockIdx.x * 256 + threadIdx.x;
    const int r = t >> 8;
    const int p = t & 255;

    const float* __restrict__ base = basis + (3 * r) * NPIX + 3 * p;
    float f[9];
    #pragma unroll
    for (int m = 0; m < 9; ++m) f[m] = 0.f;

    for (int n = 0; n < NTERMS; ++n) {
        const float* __restrict__ bn = base + (long)n * NPIX * NPIX;
        float cn = sc[n];
        #pragma unroll
        for (int s = 0; s < 3; ++s)
            #pragma unroll
            for (int q = 0; q < 3; ++q)
                f[q * 3 + s] = fmaf(bn[s * NPIX + q], cn, f[q * 3 + s]);
    }

    out[t] = climb_area(f) * 0.5f * wavel[0];
}

extern "C" void kernel_launch(void* const* d_in, const int* in_sizes, int n_in,
                              void* d_out, int out_size, void* d_ws, size_t ws_size,
                              hipStream_t stream)
{
    const float* basis  = (const float*)d_in[0];  // 128*768*768 f32
    const float* coeffs = (const float*)d_in[1];  // 128 f32
    const float* wavel  = (const float*)d_in[2];  // 1 f32
    float* out = (float*)d_out;                   // 256*256 f32

    const size_t w_bytes = (size_t)NPIX * NPIX * sizeof(float);  // 2.36 MB
    if (ws_size >= w_bytes) {
        float* W = (float*)d_ws;
        latent_kernel<<<NV4 / 192, 256, 0, stream>>>(basis, coeffs, W);
        climb_kernel<<<(PP * PP) / 256, 256, 0, stream>>>(W, wavel, out);
    } else {
        fused_kernel<<<(PP * PP) / 256, 256, 0, stream>>>(basis, coeffs, wavel, out);
    }
}